// Round 16
// baseline (173.778 us; speedup 1.0000x reference)
//
#include <hip/hip_runtime.h>
#include <hip/hip_bf16.h>

namespace {

constexpr int B_ = 2, H_ = 48, W_ = 48, DM_ = 96, DI_ = 192, NS_ = 16, RK_ = 6, K_ = 6;
constexpr int L_ = H_ * W_;
constexpr int C_ = 144;           // chunks per (b,k) stream
constexpr int LC_ = L_ / C_;      // 16 steps per chunk
constexpr int NPROJ = RK_ + 2 * NS_;  // 38
constexpr int NPAD = 48;
constexpr int WSS = NPAD + 1;

__device__ __forceinline__ float sigmoidf_(float x) { return 1.f / (1.f + __expf(-x)); }

// softplus(dtb + dts(row)·dtw(d)) — evaluated identically in fused-scan1 and scan3.
__device__ __forceinline__ float delta_of(const float* __restrict__ dp,
                                          const float* __restrict__ wdt,
                                          float bias) {
  float s = bias;
#pragma unroll
  for (int r = 0; r < RK_; ++r) s += dp[r] * wdt[r];
  return (s > 20.f) ? s : __logf(1.f + __expf(s));
}

// Row of xc/yc (pixel-major l = h*W+w) holding direction-k stream position pos.
__device__ __forceinline__ int src_row(int k, int pos) {
  int pk = (k >= 3) ? (L_ - 1 - pos) : pos;
  int kk = (k >= 3) ? k - 3 : k;
  if (kk == 0) return pk;
  int h = pk % H_, wcol = pk / H_;        // pk = wcol*H + h
  if (kk == 1) return h * W_ + wcol;
  return h * W_ + (wcol + h) % W_;        // diag: orig col = (wcol+h)%W
}

// ---------------------------------------------------------------------------
// K1: in_proj tiled GEMM.  IM=32 -> grid 432, block 256.
// ---------------------------------------------------------------------------
constexpr int IM = 32, IBK = 32;
__global__ void __launch_bounds__(256) k_inproj2(
    const float* __restrict__ x, const float* __restrict__ y,
    const float* __restrict__ kin, const float* __restrict__ inpw,
    float* __restrict__ xv, float* __restrict__ yv, float* __restrict__ zg) {
  __shared__ float As[IM][IBK + 1];
  __shared__ float Ws[IBK][DI_ + 1];
  int tid = threadIdx.x;
  constexpr int BPS = (B_ * L_) / IM;   // 144 blocks per stream
  int s = blockIdx.x / BPS;
  int row0 = (blockIdx.x % BPS) * IM;
  const float* src = (s == 0) ? x : (s == 1) ? y : kin;
  float* dst = (s == 0) ? xv : (s == 1) ? yv : zg;
  int nbase = (s == 2) ? DI_ : 0;
  int tm = tid >> 4, tn = tid & 15;     // 16 x 16
  float acc[2][12];
#pragma unroll
  for (int i = 0; i < 2; ++i)
#pragma unroll
    for (int j = 0; j < 12; ++j) acc[i][j] = 0.f;

  for (int k0 = 0; k0 < DM_; k0 += IBK) {
    {  // A tile: 32x32 = 256 float4, 1/thread
      int r = tid >> 3, c4 = (tid & 7) << 2;
      const float4 v = *reinterpret_cast<const float4*>(
          &src[(size_t)(row0 + r) * DM_ + k0 + c4]);
      As[r][c4] = v.x; As[r][c4 + 1] = v.y; As[r][c4 + 2] = v.z; As[r][c4 + 3] = v.w;
    }
#pragma unroll
    for (int it = 0; it < 6; ++it) {
      int i = tid + it * 256;        // [0,1536)
      int col = i >> 3, k4 = (i & 7) << 2;
      const float4 v = *reinterpret_cast<const float4*>(
          &inpw[(size_t)(nbase + col) * DM_ + k0 + k4]);
      Ws[k4 + 0][col] = v.x; Ws[k4 + 1][col] = v.y;
      Ws[k4 + 2][col] = v.z; Ws[k4 + 3][col] = v.w;
    }
    __syncthreads();
#pragma unroll
    for (int kk = 0; kk < IBK; ++kk) {
      float a0 = As[tm * 2 + 0][kk], a1 = As[tm * 2 + 1][kk];
      float w[12];
#pragma unroll
      for (int j = 0; j < 12; ++j) w[j] = Ws[kk][tn * 12 + j];
#pragma unroll
      for (int j = 0; j < 12; ++j) {
        acc[0][j] += a0 * w[j];
        acc[1][j] += a1 * w[j];
      }
    }
    __syncthreads();
  }
#pragma unroll
  for (int i = 0; i < 2; ++i) {
    size_t ob = (size_t)(row0 + tm * 2 + i) * DI_ + tn * 12;
#pragma unroll
    for (int j4 = 0; j4 < 3; ++j4) {
      float4 v;
      v.x = acc[i][j4 * 4 + 0]; v.y = acc[i][j4 * 4 + 1];
      v.z = acc[i][j4 * 4 + 2]; v.w = acc[i][j4 * 4 + 3];
      if (s == 2) {
        v.x *= sigmoidf_(v.x); v.y *= sigmoidf_(v.y);
        v.z *= sigmoidf_(v.z); v.w *= sigmoidf_(v.w);
      }
      *reinterpret_cast<float4*>(&dst[ob + j4 * 4]) = v;
    }
  }
}

// ---------------------------------------------------------------------------
// K2: conv 3x3 + SiLU -> xc, yc pixel-major.  grid = B*L/4 = 1152, 192 thr.
// ---------------------------------------------------------------------------
__global__ void __launch_bounds__(192) k_conv2(
    const float* __restrict__ xv, const float* __restrict__ yv,
    const float* __restrict__ cw, const float* __restrict__ cb,
    float* __restrict__ xc, float* __restrict__ yc) {
  __shared__ float scw[9 * DI_];
  int tid = threadIdx.x;
  for (int i = tid; i < 9 * DI_; i += 192) {
    int d = i / 9, j = i % 9;
    scw[j * DI_ + d] = cw[i];
  }
  __syncthreads();
  int p = tid / 48, q = tid % 48;
  int gl = blockIdx.x * 4 + p;
  int b = gl / L_, l = gl % L_;
  int h = l / W_, w = l % W_;
  int d4 = q << 2;
  float4 ax = *reinterpret_cast<const float4*>(&cb[d4]);
  float4 ay = ax;
#pragma unroll
  for (int kh = 0; kh < 3; ++kh) {
    int hh = h + kh - 1;
    if ((unsigned)hh >= (unsigned)H_) continue;
#pragma unroll
    for (int kw = 0; kw < 3; ++kw) {
      int ww = w + kw - 1;
      if ((unsigned)ww >= (unsigned)W_) continue;
      float4 wk = *reinterpret_cast<const float4*>(&scw[(kh * 3 + kw) * DI_ + d4]);
      size_t idx = ((size_t)b * L_ + hh * W_ + ww) * DI_ + d4;
      float4 vx = *reinterpret_cast<const float4*>(&xv[idx]);
      float4 vy = *reinterpret_cast<const float4*>(&yv[idx]);
      ax.x += vx.x * wk.x; ax.y += vx.y * wk.y; ax.z += vx.z * wk.z; ax.w += vx.w * wk.w;
      ay.x += vy.x * wk.x; ay.y += vy.y * wk.y; ay.z += vy.z * wk.z; ay.w += vy.w * wk.w;
    }
  }
  ax.x *= sigmoidf_(ax.x); ax.y *= sigmoidf_(ax.y);
  ax.z *= sigmoidf_(ax.z); ax.w *= sigmoidf_(ax.w);
  ay.x *= sigmoidf_(ay.x); ay.y *= sigmoidf_(ay.y);
  ay.z *= sigmoidf_(ay.z); ay.w *= sigmoidf_(ay.w);
  size_t ob = (size_t)gl * DI_ + d4;
  *reinterpret_cast<float4*>(&xc[ob]) = ax;
  *reinterpret_cast<float4*>(&yc[ob]) = ay;
}

// ---------------------------------------------------------------------------
// K3 fused: x_dbl GEMM + scan pass 1.  Block 384.  Phase 2 prefetches the
// whole chunk's u into registers (16 loads in flight) before the S-chain.
// ---------------------------------------------------------------------------
constexpr int XM = 32, XBK = 32;
__global__ void __launch_bounds__(384) k_xdbl_scan1(
    const float* __restrict__ xc, const float* __restrict__ yc,
    const float* __restrict__ xpw, const float* __restrict__ dtw,
    const float* __restrict__ dtb, const float* __restrict__ A_logs,
    float* __restrict__ dts, float* __restrict__ Bsb, float* __restrict__ Csb,
    float* __restrict__ Sdl, float* __restrict__ SHin) {
  __shared__ float As[XM][XBK + 1];
  __shared__ float Ws[XBK][WSS];
  __shared__ float xd[XM][NPAD + 1];
  int tid = threadIdx.x;
  int row0 = blockIdx.x * XM;
  int b = row0 / (K_ * L_);
  int k = (row0 / L_) % K_;
  int pos0 = row0 % L_;
  const float* usrc = ((k == 0 || k == 3) ? xc : yc) + (size_t)b * L_ * DI_;
  int tm = tid / 24, tn = tid % 24;

  if (tid < XBK * (WSS - NPROJ)) {
    int kk = tid / (WSS - NPROJ), c = NPROJ + tid % (WSS - NPROJ);
    Ws[kk][c] = 0.f;
  }
  float acc[2][2];
  acc[0][0] = acc[0][1] = acc[1][0] = acc[1][1] = 0.f;

  for (int k0 = 0; k0 < DI_; k0 += XBK) {
    if (tid < 256) {
      int r = tid >> 3, c4 = (tid & 7) << 2;
      int srow = src_row(k, pos0 + r);
      const float4 v = *reinterpret_cast<const float4*>(
          &usrc[(size_t)srow * DI_ + k0 + c4]);
      As[r][c4] = v.x; As[r][c4 + 1] = v.y; As[r][c4 + 2] = v.z; As[r][c4 + 3] = v.w;
    }
    if (tid < NPROJ * 8) {
      int c = tid >> 3, k4 = (tid & 7) << 2;
      const float4 v = *reinterpret_cast<const float4*>(
          &xpw[((size_t)k * NPROJ + c) * DI_ + k0 + k4]);
      Ws[k4 + 0][c] = v.x; Ws[k4 + 1][c] = v.y;
      Ws[k4 + 2][c] = v.z; Ws[k4 + 3][c] = v.w;
    }
    __syncthreads();
#pragma unroll
    for (int kk = 0; kk < XBK; ++kk) {
      float a0 = As[tm * 2 + 0][kk], a1 = As[tm * 2 + 1][kk];
      float w0 = Ws[kk][tn * 2 + 0], w1 = Ws[kk][tn * 2 + 1];
      acc[0][0] += a0 * w0; acc[0][1] += a0 * w1;
      acc[1][0] += a1 * w0; acc[1][1] += a1 * w1;
    }
    __syncthreads();
  }
#pragma unroll
  for (int i = 0; i < 2; ++i) {
    int r = tm * 2 + i;
    int row = row0 + r;
#pragma unroll
    for (int j = 0; j < 2; ++j) {
      int cc = tn * 2 + j;
      float v = acc[i][j];
      xd[r][cc] = v;
      if (cc < RK_) dts[(size_t)row * RK_ + cc] = v;
      else if (cc < RK_ + NS_) Bsb[(size_t)row * NS_ + (cc - RK_)] = v;
      else if (cc < NPROJ) Csb[(size_t)row * NS_ + (cc - RK_ - NS_)] = v;
    }
  }
  __syncthreads();

  // ---- phase 2: both chunks concurrently; u prefetched to registers ----
  {
    int ch = tid / DI_;        // 0 or 1
    int d = tid % DI_;
    float ureg[LC_];
#pragma unroll
    for (int l = 0; l < LC_; ++l)
      ureg[l] = usrc[(size_t)src_row(k, pos0 + ch * LC_ + l) * DI_ + d];
    float A[NS_];
#pragma unroll
    for (int n = 0; n < NS_; ++n)
      A[n] = -__expf(A_logs[((size_t)k * DI_ + d) * NS_ + n]);
    float wdt[RK_];
#pragma unroll
    for (int r = 0; r < RK_; ++r) wdt[r] = dtw[((size_t)k * DI_ + d) * RK_ + r];
    float bias = dtb[k * DI_ + d];
    float S[NS_];
#pragma unroll
    for (int n = 0; n < NS_; ++n) S[n] = 0.f;
    float sum_dl = 0.f;
#pragma unroll
    for (int l = 0; l < LC_; ++l) {
      int r = ch * LC_ + l;
      float dl = delta_of(&xd[r][0], wdt, bias);
      float du = dl * ureg[l];
      sum_dl += dl;
      const float* Bp = &xd[r][RK_];
#pragma unroll
      for (int n = 0; n < NS_; ++n) {
        float e = __expf(dl * A[n]);
        S[n] = e * S[n] + du * Bp[n];
      }
    }
    int gchunk = blockIdx.x * 2 + ch;
    Sdl[(size_t)gchunk * DI_ + d] = sum_dl;
    size_t ob = (size_t)gchunk * NS_ * DI_ + d;
#pragma unroll
    for (int n = 0; n < NS_; ++n) SHin[ob + (size_t)n * DI_] = S[n];
  }
}

// ---------------------------------------------------------------------------
// K5b: chunk-level scan, batched 8-wide load pipeline.  grid = B*K*NS = 192.
// ---------------------------------------------------------------------------
__global__ void __launch_bounds__(192) k_scan2(
    const float* __restrict__ Sdl, const float* __restrict__ A_logs,
    float* __restrict__ SHin) {
  int bkn = blockIdx.x;            // bk*NS + n
  int bk = bkn / NS_, n = bkn % NS_;
  int k = bk % K_;
  int d = threadIdx.x;
  float A = -__expf(A_logs[((size_t)k * DI_ + d) * NS_ + n]);
  float h = 0.f;
  for (int c0 = 0; c0 < C_; c0 += 8) {
    float sv[8], dv[8];
#pragma unroll
    for (int j = 0; j < 8; ++j) {   // 16 independent loads in flight
      sv[j] = SHin[((size_t)(bk * C_ + c0 + j) * NS_ + n) * DI_ + d];
      dv[j] = Sdl[(size_t)(bk * C_ + c0 + j) * DI_ + d];
    }
#pragma unroll
    for (int j = 0; j < 8; ++j) {
      float p = __expf(A * dv[j]);
      SHin[((size_t)(bk * C_ + c0 + j) * NS_ + n) * DI_ + d] = h;
      h = p * h + sv[j];
    }
  }
}

// ---------------------------------------------------------------------------
// K5c: chunked scan pass 3.  u prefetched to registers; B/C/dts LDS-staged.
// grid = 1728, 192 thr.
// ---------------------------------------------------------------------------
__global__ void __launch_bounds__(192) k_scan3(
    const float* __restrict__ dts, const float* __restrict__ dtw,
    const float* __restrict__ dtb, const float* __restrict__ xc,
    const float* __restrict__ yc, const float* __restrict__ Bsb,
    const float* __restrict__ Csb, const float* __restrict__ A_logs,
    const float* __restrict__ Ds, const float* __restrict__ SHin,
    float* __restrict__ out_y) {
  __shared__ float sB[LC_ * NS_];
  __shared__ float sC[LC_ * NS_];
  __shared__ float sdt[LC_ * RK_];
  int blk = blockIdx.x;            // bk*C_ + c
  int bk = blk / C_, c = blk % C_;
  int b = bk / K_, k = bk % K_;
  int d = threadIdx.x;
  const float* usrc = ((k == 0 || k == 3) ? xc : yc) + (size_t)b * L_ * DI_;
  int pos0 = c * LC_;
  size_t base = (size_t)bk * L_ + pos0;
  for (int i = d; i < LC_ * NS_; i += 192) {
    sB[i] = Bsb[base * NS_ + i];
    sC[i] = Csb[base * NS_ + i];
  }
  for (int i = d; i < LC_ * RK_; i += 192) sdt[i] = dts[base * RK_ + i];
  float ureg[LC_];
#pragma unroll
  for (int l = 0; l < LC_; ++l)
    ureg[l] = usrc[(size_t)src_row(k, pos0 + l) * DI_ + d];
  float A[NS_];
#pragma unroll
  for (int n = 0; n < NS_; ++n) A[n] = -__expf(A_logs[((size_t)k * DI_ + d) * NS_ + n]);
  float wdt[RK_];
#pragma unroll
  for (int r = 0; r < RK_; ++r) wdt[r] = dtw[((size_t)k * DI_ + d) * RK_ + r];
  float bias = dtb[k * DI_ + d];
  float Dk = Ds[k * DI_ + d];
  float h[NS_];
  size_t hb = (size_t)blk * NS_ * DI_ + d;
#pragma unroll
  for (int n = 0; n < NS_; ++n) h[n] = SHin[hb + (size_t)n * DI_];
  __syncthreads();
#pragma unroll
  for (int l = 0; l < LC_; ++l) {
    float dl = delta_of(&sdt[l * RK_], wdt, bias);
    float u = ureg[l];
    float du = dl * u;
    const float* Bp = &sB[l * NS_];
    const float* Cp = &sC[l * NS_];
    float yacc = 0.f;
#pragma unroll
    for (int n = 0; n < NS_; ++n) {
      h[n] = __expf(dl * A[n]) * h[n] + du * Bp[n];
      yacc += h[n] * Cp[n];
    }
    out_y[(base + l) * DI_ + d] = yacc + Dk * u;
  }
}

// ---------------------------------------------------------------------------
// K6: merge + LN + gate -> LDS, out-proj GEMM from LDS.  MT=32, grid 432.
// ---------------------------------------------------------------------------
constexpr int MT = 32, GS_ = 196;
__global__ void __launch_bounds__(256) k_head2(
    const float* __restrict__ out_y, const float* __restrict__ zg,
    const float* __restrict__ lnw, const float* __restrict__ lnb,
    const float* __restrict__ opw, float* __restrict__ out) {
  __shared__ float Gs[MT][GS_];
  __shared__ float Ws[32][DM_ + 1];
  int tid = threadIdx.x;
  constexpr int BPS = (B_ * L_) / MT;  // 144
  int m = blockIdx.x / BPS;
  int r0 = (blockIdx.x % BPS) * MT;

  {  // phase 1: 8 threads/row
    int row = tid >> 3, t8 = tid & 7;
    int bl = r0 + row;
    int b = bl / L_, lp = bl % L_;
    int h = lp / W_, w = lp % W_;
    int l0;
    if (m == 0) l0 = lp;
    else if (m == 1) l0 = w * H_ + h;
    else l0 = ((w - h + W_) % W_) * H_ + h;
    size_t basef = ((size_t)b * K_ + m) * L_;
    size_t baser = ((size_t)b * K_ + m + 3) * L_;
    const float* pf = out_y + (basef + l0) * DI_;
    const float* pr = out_y + (baser + (size_t)(L_ - 1 - l0)) * DI_;
    float s = 0.f, s2 = 0.f;
#pragma unroll
    for (int j = 0; j < 6; ++j) {
      int c4 = t8 * 24 + j * 4;
      float4 a = *reinterpret_cast<const float4*>(&pf[c4]);
      float4 bb = *reinterpret_cast<const float4*>(&pr[c4]);
      float4 t;
      t.x = a.x + bb.x; t.y = a.y + bb.y; t.z = a.z + bb.z; t.w = a.w + bb.w;
      s += t.x + t.y + t.z + t.w;
      s2 += t.x * t.x + t.y * t.y + t.z * t.z + t.w * t.w;
      *reinterpret_cast<float4*>(&Gs[row][c4]) = t;
    }
    s += __shfl_xor(s, 1, 64);  s2 += __shfl_xor(s2, 1, 64);
    s += __shfl_xor(s, 2, 64);  s2 += __shfl_xor(s2, 2, 64);
    s += __shfl_xor(s, 4, 64);  s2 += __shfl_xor(s2, 4, 64);
    float mu = s * (1.f / DI_);
    float var = fmaxf(s2 * (1.f / DI_) - mu * mu, 0.f);
    float rs = rsqrtf(var + 1e-5f);
    const float* zp = zg + (size_t)bl * DI_;
#pragma unroll
    for (int j = 0; j < 6; ++j) {
      int c4 = t8 * 24 + j * 4;
      float4 t = *reinterpret_cast<const float4*>(&Gs[row][c4]);
      float4 zv = *reinterpret_cast<const float4*>(&zp[c4]);
      t.x = ((t.x - mu) * rs * lnw[c4 + 0] + lnb[c4 + 0]) * zv.x;
      t.y = ((t.y - mu) * rs * lnw[c4 + 1] + lnb[c4 + 1]) * zv.y;
      t.z = ((t.z - mu) * rs * lnw[c4 + 2] + lnb[c4 + 2]) * zv.z;
      t.w = ((t.w - mu) * rs * lnw[c4 + 3] + lnb[c4 + 3]) * zv.w;
      *reinterpret_cast<float4*>(&Gs[row][c4]) = t;
    }
  }
  __syncthreads();

  int tm = tid >> 4, tn = tid & 15;
  float acc[2][6];
#pragma unroll
  for (int i = 0; i < 2; ++i)
#pragma unroll
    for (int j = 0; j < 6; ++j) acc[i][j] = 0.f;

  for (int k0 = 0; k0 < DI_; k0 += 32) {
#pragma unroll
    for (int it = 0; it < 3; ++it) {
      int i = tid + it * 256;        // [0,768)
      int o = i >> 3, k4 = (i & 7) << 2;
      const float4 v = *reinterpret_cast<const float4*>(
          &opw[(size_t)o * DI_ + k0 + k4]);
      Ws[k4 + 0][o] = v.x; Ws[k4 + 1][o] = v.y;
      Ws[k4 + 2][o] = v.z; Ws[k4 + 3][o] = v.w;
    }
    __syncthreads();
#pragma unroll
    for (int kk = 0; kk < 32; ++kk) {
      float a0 = Gs[tm * 2 + 0][k0 + kk], a1 = Gs[tm * 2 + 1][k0 + kk];
      float w[6];
#pragma unroll
      for (int j = 0; j < 6; ++j) w[j] = Ws[kk][tn * 6 + j];
#pragma unroll
      for (int j = 0; j < 6; ++j) {
        acc[0][j] += a0 * w[j];
        acc[1][j] += a1 * w[j];
      }
    }
    __syncthreads();
  }
  size_t obase = ((size_t)m * (B_ * L_) + r0) * DM_;
#pragma unroll
  for (int i = 0; i < 2; ++i) {
    size_t ob = obase + (size_t)(tm * 2 + i) * DM_ + tn * 6;
#pragma unroll
    for (int j = 0; j < 6; ++j) out[ob + j] = acc[i][j];
  }
}

}  // namespace

extern "C" void kernel_launch(void* const* d_in, const int* in_sizes, int n_in,
                              void* d_out, int out_size, void* d_ws, size_t ws_size,
                              hipStream_t stream) {
  const float* x = (const float*)d_in[0];
  const float* y = (const float*)d_in[1];
  const float* kin = (const float*)d_in[2];
  const float* in_proj_w = (const float*)d_in[3];
  const float* conv_w = (const float*)d_in[4];
  const float* conv_b = (const float*)d_in[5];
  const float* x_proj_w = (const float*)d_in[6];
  const float* dt_w = (const float*)d_in[7];
  const float* dt_b = (const float*)d_in[8];
  const float* A_logs = (const float*)d_in[9];
  const float* Ds = (const float*)d_in[10];
  const float* ln_w = (const float*)d_in[11];
  const float* ln_b = (const float*)d_in[12];
  const float* out_proj_w = (const float*)d_in[13];
  float* out = (float*)d_out;

  float* ws = (float*)d_ws;
  const size_t BLD = (size_t)B_ * L_ * DI_;
  const size_t BKLD = (size_t)B_ * K_ * L_ * DI_;
  const size_t BKLN = (size_t)B_ * K_ * L_ * NS_;
  const size_t PSN = (size_t)B_ * K_ * C_ * NS_ * DI_;
  float* xv = ws;     ws += BLD;
  float* yv = ws;     ws += BLD;
  float* zg = ws;     ws += BLD;
  float* xc = ws;     ws += BLD;
  float* yc = ws;     ws += BLD;
  float* Bsb = ws;    ws += BKLN;
  float* Csb = ws;    ws += BKLN;
  float* out_y = ws;  ws += BKLD;
  float* SHin = ws;   ws += PSN;
  float* Sdl = ws;    ws += (size_t)B_ * K_ * C_ * DI_;
  float* dts = ws;    ws += (size_t)B_ * K_ * L_ * RK_;

  k_inproj2<<<3 * B_ * L_ / IM, 256, 0, stream>>>(x, y, kin, in_proj_w, xv, yv, zg);
  k_conv2<<<B_ * L_ / 4, 192, 0, stream>>>(xv, yv, conv_w, conv_b, xc, yc);
  k_xdbl_scan1<<<B_ * K_ * L_ / XM, 384, 0, stream>>>(xc, yc, x_proj_w, dt_w, dt_b,
                                                      A_logs, dts, Bsb, Csb, Sdl, SHin);
  k_scan2<<<B_ * K_ * NS_, 192, 0, stream>>>(Sdl, A_logs, SHin);
  k_scan3<<<B_ * K_ * C_, 192, 0, stream>>>(dts, dt_w, dt_b, xc, yc, Bsb, Csb,
                                            A_logs, Ds, SHin, out_y);
  k_head2<<<3 * B_ * L_ / MT, 256, 0, stream>>>(out_y, zg, ln_w, ln_b, out_proj_w, out);
}

// Round 17
// 141.301 us; speedup vs baseline: 1.2298x; 1.2298x over previous
//
#include <hip/hip_runtime.h>
#include <hip/hip_bf16.h>

namespace {

constexpr int B_ = 2, H_ = 48, W_ = 48, DM_ = 96, DI_ = 192, NS_ = 16, RK_ = 6, K_ = 6;
constexpr int L_ = H_ * W_;
constexpr int C_ = 144;           // chunks per (b,k) stream
constexpr int LC_ = L_ / C_;      // 16 steps per chunk
constexpr int NPROJ = RK_ + 2 * NS_;  // 38
constexpr int NPAD = 48;
constexpr int WSS = NPAD + 1;

__device__ __forceinline__ float sigmoidf_(float x) { return 1.f / (1.f + __expf(-x)); }

// softplus(dtb + dts(row)·dtw(d)) — evaluated identically in fused-scan1 and scan3.
__device__ __forceinline__ float delta_of(const float* __restrict__ dp,
                                          const float* __restrict__ wdt,
                                          float bias) {
  float s = bias;
#pragma unroll
  for (int r = 0; r < RK_; ++r) s += dp[r] * wdt[r];
  return (s > 20.f) ? s : __logf(1.f + __expf(s));
}

// Row of xc/yc (pixel-major l = h*W+w) holding direction-k stream position pos.
__device__ __forceinline__ int src_row(int k, int pos) {
  int pk = (k >= 3) ? (L_ - 1 - pos) : pos;
  int kk = (k >= 3) ? k - 3 : k;
  if (kk == 0) return pk;
  int h = pk % H_, wcol = pk / H_;        // pk = wcol*H + h
  if (kk == 1) return h * W_ + wcol;
  return h * W_ + (wcol + h) % W_;        // diag: orig col = (wcol+h)%W
}

// ---------------------------------------------------------------------------
// K1: in_proj tiled GEMM.  IM=32 -> grid 432, block 256.
// ---------------------------------------------------------------------------
constexpr int IM = 32, IBK = 32;
__global__ void __launch_bounds__(256) k_inproj2(
    const float* __restrict__ x, const float* __restrict__ y,
    const float* __restrict__ kin, const float* __restrict__ inpw,
    float* __restrict__ xv, float* __restrict__ yv, float* __restrict__ zg) {
  __shared__ float As[IM][IBK + 1];
  __shared__ float Ws[IBK][DI_ + 1];
  int tid = threadIdx.x;
  constexpr int BPS = (B_ * L_) / IM;   // 144 blocks per stream
  int s = blockIdx.x / BPS;
  int row0 = (blockIdx.x % BPS) * IM;
  const float* src = (s == 0) ? x : (s == 1) ? y : kin;
  float* dst = (s == 0) ? xv : (s == 1) ? yv : zg;
  int nbase = (s == 2) ? DI_ : 0;
  int tm = tid >> 4, tn = tid & 15;     // 16 x 16
  float acc[2][12];
#pragma unroll
  for (int i = 0; i < 2; ++i)
#pragma unroll
    for (int j = 0; j < 12; ++j) acc[i][j] = 0.f;

  for (int k0 = 0; k0 < DM_; k0 += IBK) {
    {  // A tile: 32x32 = 256 float4, 1/thread
      int r = tid >> 3, c4 = (tid & 7) << 2;
      const float4 v = *reinterpret_cast<const float4*>(
          &src[(size_t)(row0 + r) * DM_ + k0 + c4]);
      As[r][c4] = v.x; As[r][c4 + 1] = v.y; As[r][c4 + 2] = v.z; As[r][c4 + 3] = v.w;
    }
#pragma unroll
    for (int it = 0; it < 6; ++it) {
      int i = tid + it * 256;        // [0,1536)
      int col = i >> 3, k4 = (i & 7) << 2;
      const float4 v = *reinterpret_cast<const float4*>(
          &inpw[(size_t)(nbase + col) * DM_ + k0 + k4]);
      Ws[k4 + 0][col] = v.x; Ws[k4 + 1][col] = v.y;
      Ws[k4 + 2][col] = v.z; Ws[k4 + 3][col] = v.w;
    }
    __syncthreads();
#pragma unroll
    for (int kk = 0; kk < IBK; ++kk) {
      float a0 = As[tm * 2 + 0][kk], a1 = As[tm * 2 + 1][kk];
      float w[12];
#pragma unroll
      for (int j = 0; j < 12; ++j) w[j] = Ws[kk][tn * 12 + j];
#pragma unroll
      for (int j = 0; j < 12; ++j) {
        acc[0][j] += a0 * w[j];
        acc[1][j] += a1 * w[j];
      }
    }
    __syncthreads();
  }
#pragma unroll
  for (int i = 0; i < 2; ++i) {
    size_t ob = (size_t)(row0 + tm * 2 + i) * DI_ + tn * 12;
#pragma unroll
    for (int j4 = 0; j4 < 3; ++j4) {
      float4 v;
      v.x = acc[i][j4 * 4 + 0]; v.y = acc[i][j4 * 4 + 1];
      v.z = acc[i][j4 * 4 + 2]; v.w = acc[i][j4 * 4 + 3];
      if (s == 2) {
        v.x *= sigmoidf_(v.x); v.y *= sigmoidf_(v.y);
        v.z *= sigmoidf_(v.z); v.w *= sigmoidf_(v.w);
      }
      *reinterpret_cast<float4*>(&dst[ob + j4 * 4]) = v;
    }
  }
}

// ---------------------------------------------------------------------------
// K2: conv 3x3 + SiLU -> xc, yc pixel-major.  grid = B*L/4 = 1152, 192 thr.
// ---------------------------------------------------------------------------
__global__ void __launch_bounds__(192) k_conv2(
    const float* __restrict__ xv, const float* __restrict__ yv,
    const float* __restrict__ cw, const float* __restrict__ cb,
    float* __restrict__ xc, float* __restrict__ yc) {
  __shared__ float scw[9 * DI_];
  int tid = threadIdx.x;
  for (int i = tid; i < 9 * DI_; i += 192) {
    int d = i / 9, j = i % 9;
    scw[j * DI_ + d] = cw[i];
  }
  __syncthreads();
  int p = tid / 48, q = tid % 48;
  int gl = blockIdx.x * 4 + p;
  int b = gl / L_, l = gl % L_;
  int h = l / W_, w = l % W_;
  int d4 = q << 2;
  float4 ax = *reinterpret_cast<const float4*>(&cb[d4]);
  float4 ay = ax;
#pragma unroll
  for (int kh = 0; kh < 3; ++kh) {
    int hh = h + kh - 1;
    if ((unsigned)hh >= (unsigned)H_) continue;
#pragma unroll
    for (int kw = 0; kw < 3; ++kw) {
      int ww = w + kw - 1;
      if ((unsigned)ww >= (unsigned)W_) continue;
      float4 wk = *reinterpret_cast<const float4*>(&scw[(kh * 3 + kw) * DI_ + d4]);
      size_t idx = ((size_t)b * L_ + hh * W_ + ww) * DI_ + d4;
      float4 vx = *reinterpret_cast<const float4*>(&xv[idx]);
      float4 vy = *reinterpret_cast<const float4*>(&yv[idx]);
      ax.x += vx.x * wk.x; ax.y += vx.y * wk.y; ax.z += vx.z * wk.z; ax.w += vx.w * wk.w;
      ay.x += vy.x * wk.x; ay.y += vy.y * wk.y; ay.z += vy.z * wk.z; ay.w += vy.w * wk.w;
    }
  }
  ax.x *= sigmoidf_(ax.x); ax.y *= sigmoidf_(ax.y);
  ax.z *= sigmoidf_(ax.z); ax.w *= sigmoidf_(ax.w);
  ay.x *= sigmoidf_(ay.x); ay.y *= sigmoidf_(ay.y);
  ay.z *= sigmoidf_(ay.z); ay.w *= sigmoidf_(ay.w);
  size_t ob = (size_t)gl * DI_ + d4;
  *reinterpret_cast<float4*>(&xc[ob]) = ax;
  *reinterpret_cast<float4*>(&yc[ob]) = ay;
}

// ---------------------------------------------------------------------------
// K3 fused: x_dbl GEMM + scan pass 1.  Block 384.  Phase 2 reads u directly
// from global (L2-hot) inside the chain — low VGPR, high occupancy.
// ---------------------------------------------------------------------------
constexpr int XM = 32, XBK = 32;
__global__ void __launch_bounds__(384) k_xdbl_scan1(
    const float* __restrict__ xc, const float* __restrict__ yc,
    const float* __restrict__ xpw, const float* __restrict__ dtw,
    const float* __restrict__ dtb, const float* __restrict__ A_logs,
    float* __restrict__ dts, float* __restrict__ Bsb, float* __restrict__ Csb,
    float* __restrict__ Sdl, float* __restrict__ SHin) {
  __shared__ float As[XM][XBK + 1];
  __shared__ float Ws[XBK][WSS];
  __shared__ float xd[XM][NPAD + 1];
  int tid = threadIdx.x;
  int row0 = blockIdx.x * XM;
  int b = row0 / (K_ * L_);
  int k = (row0 / L_) % K_;
  int pos0 = row0 % L_;
  const float* usrc = ((k == 0 || k == 3) ? xc : yc) + (size_t)b * L_ * DI_;
  int tm = tid / 24, tn = tid % 24;

  if (tid < XBK * (WSS - NPROJ)) {
    int kk = tid / (WSS - NPROJ), c = NPROJ + tid % (WSS - NPROJ);
    Ws[kk][c] = 0.f;
  }
  float acc[2][2];
  acc[0][0] = acc[0][1] = acc[1][0] = acc[1][1] = 0.f;

  for (int k0 = 0; k0 < DI_; k0 += XBK) {
    if (tid < 256) {
      int r = tid >> 3, c4 = (tid & 7) << 2;
      int srow = src_row(k, pos0 + r);
      const float4 v = *reinterpret_cast<const float4*>(
          &usrc[(size_t)srow * DI_ + k0 + c4]);
      As[r][c4] = v.x; As[r][c4 + 1] = v.y; As[r][c4 + 2] = v.z; As[r][c4 + 3] = v.w;
    }
    if (tid < NPROJ * 8) {
      int c = tid >> 3, k4 = (tid & 7) << 2;
      const float4 v = *reinterpret_cast<const float4*>(
          &xpw[((size_t)k * NPROJ + c) * DI_ + k0 + k4]);
      Ws[k4 + 0][c] = v.x; Ws[k4 + 1][c] = v.y;
      Ws[k4 + 2][c] = v.z; Ws[k4 + 3][c] = v.w;
    }
    __syncthreads();
#pragma unroll
    for (int kk = 0; kk < XBK; ++kk) {
      float a0 = As[tm * 2 + 0][kk], a1 = As[tm * 2 + 1][kk];
      float w0 = Ws[kk][tn * 2 + 0], w1 = Ws[kk][tn * 2 + 1];
      acc[0][0] += a0 * w0; acc[0][1] += a0 * w1;
      acc[1][0] += a1 * w0; acc[1][1] += a1 * w1;
    }
    __syncthreads();
  }
#pragma unroll
  for (int i = 0; i < 2; ++i) {
    int r = tm * 2 + i;
    int row = row0 + r;
#pragma unroll
    for (int j = 0; j < 2; ++j) {
      int cc = tn * 2 + j;
      float v = acc[i][j];
      xd[r][cc] = v;
      if (cc < RK_) dts[(size_t)row * RK_ + cc] = v;
      else if (cc < RK_ + NS_) Bsb[(size_t)row * NS_ + (cc - RK_)] = v;
      else if (cc < NPROJ) Csb[(size_t)row * NS_ + (cc - RK_ - NS_)] = v;
    }
  }
  __syncthreads();

  // ---- phase 2: both chunks concurrently; u from global, B/dts from LDS ----
  {
    int ch = tid / DI_;        // 0 or 1
    int d = tid % DI_;
    float A[NS_];
#pragma unroll
    for (int n = 0; n < NS_; ++n)
      A[n] = -__expf(A_logs[((size_t)k * DI_ + d) * NS_ + n]);
    float wdt[RK_];
#pragma unroll
    for (int r = 0; r < RK_; ++r) wdt[r] = dtw[((size_t)k * DI_ + d) * RK_ + r];
    float bias = dtb[k * DI_ + d];
    float S[NS_];
#pragma unroll
    for (int n = 0; n < NS_; ++n) S[n] = 0.f;
    float sum_dl = 0.f;
    for (int l = 0; l < LC_; ++l) {
      int r = ch * LC_ + l;
      float dl = delta_of(&xd[r][0], wdt, bias);
      float u = usrc[(size_t)src_row(k, pos0 + r) * DI_ + d];
      float du = dl * u;
      sum_dl += dl;
      const float* Bp = &xd[r][RK_];
#pragma unroll
      for (int n = 0; n < NS_; ++n) {
        float e = __expf(dl * A[n]);
        S[n] = e * S[n] + du * Bp[n];
      }
    }
    int gchunk = blockIdx.x * 2 + ch;
    Sdl[(size_t)gchunk * DI_ + d] = sum_dl;
    size_t ob = (size_t)gchunk * NS_ * DI_ + d;
#pragma unroll
    for (int n = 0; n < NS_; ++n) SHin[ob + (size_t)n * DI_] = S[n];
  }
}

// ---------------------------------------------------------------------------
// K5b: chunk-level scan, batched 8-wide load pipeline.  grid = B*K*NS = 192.
// ---------------------------------------------------------------------------
__global__ void __launch_bounds__(192) k_scan2(
    const float* __restrict__ Sdl, const float* __restrict__ A_logs,
    float* __restrict__ SHin) {
  int bkn = blockIdx.x;            // bk*NS + n
  int bk = bkn / NS_, n = bkn % NS_;
  int k = bk % K_;
  int d = threadIdx.x;
  float A = -__expf(A_logs[((size_t)k * DI_ + d) * NS_ + n]);
  float h = 0.f;
  for (int c0 = 0; c0 < C_; c0 += 8) {
    float sv[8], dv[8];
#pragma unroll
    for (int j = 0; j < 8; ++j) {   // 16 independent loads in flight
      sv[j] = SHin[((size_t)(bk * C_ + c0 + j) * NS_ + n) * DI_ + d];
      dv[j] = Sdl[(size_t)(bk * C_ + c0 + j) * DI_ + d];
    }
#pragma unroll
    for (int j = 0; j < 8; ++j) {
      float p = __expf(A * dv[j]);
      SHin[((size_t)(bk * C_ + c0 + j) * NS_ + n) * DI_ + d] = h;
      h = p * h + sv[j];
    }
  }
}

// ---------------------------------------------------------------------------
// K5c: chunked scan pass 3.  u prefetched to registers; B/C/dts LDS-staged.
// grid = 1728, 192 thr.
// ---------------------------------------------------------------------------
__global__ void __launch_bounds__(192) k_scan3(
    const float* __restrict__ dts, const float* __restrict__ dtw,
    const float* __restrict__ dtb, const float* __restrict__ xc,
    const float* __restrict__ yc, const float* __restrict__ Bsb,
    const float* __restrict__ Csb, const float* __restrict__ A_logs,
    const float* __restrict__ Ds, const float* __restrict__ SHin,
    float* __restrict__ out_y) {
  __shared__ float sB[LC_ * NS_];
  __shared__ float sC[LC_ * NS_];
  __shared__ float sdt[LC_ * RK_];
  int blk = blockIdx.x;            // bk*C_ + c
  int bk = blk / C_, c = blk % C_;
  int b = bk / K_, k = bk % K_;
  int d = threadIdx.x;
  const float* usrc = ((k == 0 || k == 3) ? xc : yc) + (size_t)b * L_ * DI_;
  int pos0 = c * LC_;
  size_t base = (size_t)bk * L_ + pos0;
  for (int i = d; i < LC_ * NS_; i += 192) {
    sB[i] = Bsb[base * NS_ + i];
    sC[i] = Csb[base * NS_ + i];
  }
  for (int i = d; i < LC_ * RK_; i += 192) sdt[i] = dts[base * RK_ + i];
  float ureg[LC_];
#pragma unroll
  for (int l = 0; l < LC_; ++l)
    ureg[l] = usrc[(size_t)src_row(k, pos0 + l) * DI_ + d];
  float A[NS_];
#pragma unroll
  for (int n = 0; n < NS_; ++n) A[n] = -__expf(A_logs[((size_t)k * DI_ + d) * NS_ + n]);
  float wdt[RK_];
#pragma unroll
  for (int r = 0; r < RK_; ++r) wdt[r] = dtw[((size_t)k * DI_ + d) * RK_ + r];
  float bias = dtb[k * DI_ + d];
  float Dk = Ds[k * DI_ + d];
  float h[NS_];
  size_t hb = (size_t)blk * NS_ * DI_ + d;
#pragma unroll
  for (int n = 0; n < NS_; ++n) h[n] = SHin[hb + (size_t)n * DI_];
  __syncthreads();
#pragma unroll
  for (int l = 0; l < LC_; ++l) {
    float dl = delta_of(&sdt[l * RK_], wdt, bias);
    float u = ureg[l];
    float du = dl * u;
    const float* Bp = &sB[l * NS_];
    const float* Cp = &sC[l * NS_];
    float yacc = 0.f;
#pragma unroll
    for (int n = 0; n < NS_; ++n) {
      h[n] = __expf(dl * A[n]) * h[n] + du * Bp[n];
      yacc += h[n] * Cp[n];
    }
    out_y[(base + l) * DI_ + d] = yacc + Dk * u;
  }
}

// ---------------------------------------------------------------------------
// K6: merge + LN + gate -> LDS, out-proj GEMM from LDS.  MT=32, grid 432.
// ---------------------------------------------------------------------------
constexpr int MT = 32, GS_ = 196;
__global__ void __launch_bounds__(256) k_head2(
    const float* __restrict__ out_y, const float* __restrict__ zg,
    const float* __restrict__ lnw, const float* __restrict__ lnb,
    const float* __restrict__ opw, float* __restrict__ out) {
  __shared__ float Gs[MT][GS_];
  __shared__ float Ws[32][DM_ + 1];
  int tid = threadIdx.x;
  constexpr int BPS = (B_ * L_) / MT;  // 144
  int m = blockIdx.x / BPS;
  int r0 = (blockIdx.x % BPS) * MT;

  {  // phase 1: 8 threads/row
    int row = tid >> 3, t8 = tid & 7;
    int bl = r0 + row;
    int b = bl / L_, lp = bl % L_;
    int h = lp / W_, w = lp % W_;
    int l0;
    if (m == 0) l0 = lp;
    else if (m == 1) l0 = w * H_ + h;
    else l0 = ((w - h + W_) % W_) * H_ + h;
    size_t basef = ((size_t)b * K_ + m) * L_;
    size_t baser = ((size_t)b * K_ + m + 3) * L_;
    const float* pf = out_y + (basef + l0) * DI_;
    const float* pr = out_y + (baser + (size_t)(L_ - 1 - l0)) * DI_;
    float s = 0.f, s2 = 0.f;
#pragma unroll
    for (int j = 0; j < 6; ++j) {
      int c4 = t8 * 24 + j * 4;
      float4 a = *reinterpret_cast<const float4*>(&pf[c4]);
      float4 bb = *reinterpret_cast<const float4*>(&pr[c4]);
      float4 t;
      t.x = a.x + bb.x; t.y = a.y + bb.y; t.z = a.z + bb.z; t.w = a.w + bb.w;
      s += t.x + t.y + t.z + t.w;
      s2 += t.x * t.x + t.y * t.y + t.z * t.z + t.w * t.w;
      *reinterpret_cast<float4*>(&Gs[row][c4]) = t;
    }
    s += __shfl_xor(s, 1, 64);  s2 += __shfl_xor(s2, 1, 64);
    s += __shfl_xor(s, 2, 64);  s2 += __shfl_xor(s2, 2, 64);
    s += __shfl_xor(s, 4, 64);  s2 += __shfl_xor(s2, 4, 64);
    float mu = s * (1.f / DI_);
    float var = fmaxf(s2 * (1.f / DI_) - mu * mu, 0.f);
    float rs = rsqrtf(var + 1e-5f);
    const float* zp = zg + (size_t)bl * DI_;
#pragma unroll
    for (int j = 0; j < 6; ++j) {
      int c4 = t8 * 24 + j * 4;
      float4 t = *reinterpret_cast<const float4*>(&Gs[row][c4]);
      float4 zv = *reinterpret_cast<const float4*>(&zp[c4]);
      t.x = ((t.x - mu) * rs * lnw[c4 + 0] + lnb[c4 + 0]) * zv.x;
      t.y = ((t.y - mu) * rs * lnw[c4 + 1] + lnb[c4 + 1]) * zv.y;
      t.z = ((t.z - mu) * rs * lnw[c4 + 2] + lnb[c4 + 2]) * zv.z;
      t.w = ((t.w - mu) * rs * lnw[c4 + 3] + lnb[c4 + 3]) * zv.w;
      *reinterpret_cast<float4*>(&Gs[row][c4]) = t;
    }
  }
  __syncthreads();

  int tm = tid >> 4, tn = tid & 15;
  float acc[2][6];
#pragma unroll
  for (int i = 0; i < 2; ++i)
#pragma unroll
    for (int j = 0; j < 6; ++j) acc[i][j] = 0.f;

  for (int k0 = 0; k0 < DI_; k0 += 32) {
#pragma unroll
    for (int it = 0; it < 3; ++it) {
      int i = tid + it * 256;        // [0,768)
      int o = i >> 3, k4 = (i & 7) << 2;
      const float4 v = *reinterpret_cast<const float4*>(
          &opw[(size_t)o * DI_ + k0 + k4]);
      Ws[k4 + 0][o] = v.x; Ws[k4 + 1][o] = v.y;
      Ws[k4 + 2][o] = v.z; Ws[k4 + 3][o] = v.w;
    }
    __syncthreads();
#pragma unroll
    for (int kk = 0; kk < 32; ++kk) {
      float a0 = Gs[tm * 2 + 0][k0 + kk], a1 = Gs[tm * 2 + 1][k0 + kk];
      float w[6];
#pragma unroll
      for (int j = 0; j < 6; ++j) w[j] = Ws[kk][tn * 6 + j];
#pragma unroll
      for (int j = 0; j < 6; ++j) {
        acc[0][j] += a0 * w[j];
        acc[1][j] += a1 * w[j];
      }
    }
    __syncthreads();
  }
  size_t obase = ((size_t)m * (B_ * L_) + r0) * DM_;
#pragma unroll
  for (int i = 0; i < 2; ++i) {
    size_t ob = obase + (size_t)(tm * 2 + i) * DM_ + tn * 6;
#pragma unroll
    for (int j = 0; j < 6; ++j) out[ob + j] = acc[i][j];
  }
}

}  // namespace

extern "C" void kernel_launch(void* const* d_in, const int* in_sizes, int n_in,
                              void* d_out, int out_size, void* d_ws, size_t ws_size,
                              hipStream_t stream) {
  const float* x = (const float*)d_in[0];
  const float* y = (const float*)d_in[1];
  const float* kin = (const float*)d_in[2];
  const float* in_proj_w = (const float*)d_in[3];
  const float* conv_w = (const float*)d_in[4];
  const float* conv_b = (const float*)d_in[5];
  const float* x_proj_w = (const float*)d_in[6];
  const float* dt_w = (const float*)d_in[7];
  const float* dt_b = (const float*)d_in[8];
  const float* A_logs = (const float*)d_in[9];
  const float* Ds = (const float*)d_in[10];
  const float* ln_w = (const float*)d_in[11];
  const float* ln_b = (const float*)d_in[12];
  const float* out_proj_w = (const float*)d_in[13];
  float* out = (float*)d_out;

  float* ws = (float*)d_ws;
  const size_t BLD = (size_t)B_ * L_ * DI_;
  const size_t BKLD = (size_t)B_ * K_ * L_ * DI_;
  const size_t BKLN = (size_t)B_ * K_ * L_ * NS_;
  const size_t PSN = (size_t)B_ * K_ * C_ * NS_ * DI_;
  float* xv = ws;     ws += BLD;
  float* yv = ws;     ws += BLD;
  float* zg = ws;     ws += BLD;
  float* xc = ws;     ws += BLD;
  float* yc = ws;     ws += BLD;
  float* Bsb = ws;    ws += BKLN;
  float* Csb = ws;    ws += BKLN;
  float* out_y = ws;  ws += BKLD;
  float* SHin = ws;   ws += PSN;
  float* Sdl = ws;    ws += (size_t)B_ * K_ * C_ * DI_;
  float* dts = ws;    ws += (size_t)B_ * K_ * L_ * RK_;

  k_inproj2<<<3 * B_ * L_ / IM, 256, 0, stream>>>(x, y, kin, in_proj_w, xv, yv, zg);
  k_conv2<<<B_ * L_ / 4, 192, 0, stream>>>(xv, yv, conv_w, conv_b, xc, yc);
  k_xdbl_scan1<<<B_ * K_ * L_ / XM, 384, 0, stream>>>(xc, yc, x_proj_w, dt_w, dt_b,
                                                      A_logs, dts, Bsb, Csb, Sdl, SHin);
  k_scan2<<<B_ * K_ * NS_, 192, 0, stream>>>(Sdl, A_logs, SHin);
  k_scan3<<<B_ * K_ * C_, 192, 0, stream>>>(dts, dt_w, dt_b, xc, yc, Bsb, Csb,
                                            A_logs, Ds, SHin, out_y);
  k_head2<<<3 * B_ * L_ / MT, 256, 0, stream>>>(out_y, zg, ln_w, ln_b, out_proj_w, out);
}